// Round 18
// baseline (175.954 us; speedup 1.0000x reference)
//
#include <hip/hip_runtime.h>
#include <hip/hip_bf16.h>

typedef __bf16 bf16x8_t __attribute__((ext_vector_type(8)));
typedef __bf16 bf16x4_t __attribute__((ext_vector_type(4)));
typedef float f32x4_t __attribute__((ext_vector_type(4)));
typedef float f32x16_t __attribute__((ext_vector_type(16)));

__device__ __forceinline__ void gload_lds16(const void* g, void* l) {
    __builtin_amdgcn_global_load_lds((const __attribute__((address_space(1))) void*)g,
                                     (__attribute__((address_space(3))) void*)l, 16, 0, 0);
}

__device__ __forceinline__ unsigned pk_bf16(float a, float b) {
    unsigned r;
    asm("v_cvt_pk_bf16_f32 %0, %1, %2" : "=v"(r) : "v"(a), "v"(b));
    return r;
}

// ---------------- fused fp32 -> bf16 conversion (x, w_attn, w_proj) ----------------
__global__ void f2bf3_kernel(const float* __restrict__ x, const float* __restrict__ wa,
                             const float* __restrict__ wp, __bf16* __restrict__ xb,
                             __bf16* __restrict__ wab, __bf16* __restrict__ wpb) {
    int i = blockIdx.x * blockDim.x + threadIdx.x;   // float4 index, total 3145728
    const float* in; __bf16* out; int off;
    if (i < 2097152)      { in = x;  out = xb;  off = i; }
    else if (i < 2883584) { in = wa; out = wab; off = i - 2097152; }
    else                  { in = wp; out = wpb; off = i - 2883584; }
    float4 v = *(const float4*)(in + off * 4);
    bf16x4_t o;
    o[0] = (__bf16)v.x; o[1] = (__bf16)v.y; o[2] = (__bf16)v.z; o[3] = (__bf16)v.w;
    *(bf16x4_t*)(out + off * 4) = o;
}

// ---------------- 8-phase 256x128 GEMM core (proven R17), two epilogues ----------------
// 8 waves (2M x 4N), per-wave 128x32 (acc[8][2]). LDS 96 KB dbuf.
// Ledger (A=4/tile split 2+2, B=2/tile split 1+1):
//   prologue: t0 (6) + B(t1) (2), vmcnt(2);
//   ph1,2: stage A(t1); ph3,4: stage B(t2), vmcnt(2)@ph4;
//   ph5,6: stage A(t2); ph7,8: stage B(t3), vmcnt(2)@ph8; lastit: vmcnt(0).

// GEMM1: qkv = x @ w_attn^T; Q/K cols -> Cqk [8192][2048], V cols -> Vg transposed.
// grid 768 = 32(M) x 24(N) = 3 full CU-waves, zero tail. 2048 % 128 == 0 -> uniform branch.
__global__ __launch_bounds__(512, 2) void gemm1_m201(const __bf16* __restrict__ A,
                                                     const __bf16* __restrict__ Bt,
                                                     __bf16* __restrict__ Cqk,
                                                     __bf16* __restrict__ Vg,
                                                     int M, int N, int K) {
    __shared__ __bf16 As[2][256 * 64];
    __shared__ __bf16 Bs[2][128 * 64];

    const int tid  = threadIdx.x;
    const int lane = tid & 63;
    const int wid  = tid >> 6;
    const int wm   = wid >> 2;
    const int wn   = wid & 3;

    int fl = blockIdx.x;
    fl = (fl & 7) * (gridDim.x >> 3) + (fl >> 3);   // 768 % 8 == 0 -> bijective
    const int m0 = (fl / 24) * 256;
    const int n0 = (fl % 24) * 128;

    const int lr = lane & 15;
    const int lg = lane >> 4;
    const int cr = lg * 4;
    const int srow = lane >> 3;
    const int gcol = (((lane & 7) ^ srow) << 3);

    f32x4_t acc[8][2];
#pragma unroll
    for (int i = 0; i < 8; ++i)
#pragma unroll
        for (int j = 0; j < 2; ++j)
            acc[i][j] = (f32x4_t){0.f, 0.f, 0.f, 0.f};

    const int NT = K >> 6;
    const int NI = NT >> 1;

    bf16x8_t af[4][2], bf0[1][2], bf1[1][2];

    auto stA = [&](int kt, int buf, int half) {
        const __bf16* Ab = A + (size_t)m0 * K + (size_t)kt * 64;
        const int s0 = half * 16 + wid, s1 = s0 + 8;
        gload_lds16(Ab + (size_t)(s0 * 8 + srow) * K + gcol, &As[buf][s0 * 512]);
        gload_lds16(Ab + (size_t)(s1 * 8 + srow) * K + gcol, &As[buf][s1 * 512]);
    };
    auto stBlo = [&](int kt, int buf) {
        const __bf16* Bb = Bt + (size_t)n0 * K + (size_t)kt * 64;
        gload_lds16(Bb + (size_t)(wid * 8 + srow) * K + gcol, &Bs[buf][wid * 512]);
    };
    auto stBhi = [&](int kt, int buf) {
        const __bf16* Bb = Bt + (size_t)n0 * K + (size_t)kt * 64;
        gload_lds16(Bb + (size_t)((wid + 8) * 8 + srow) * K + gcol, &Bs[buf][(wid + 8) * 512]);
    };
    auto dsA = [&](const __bf16* Ab, int mfh) {
#pragma unroll
        for (int mf = 0; mf < 4; ++mf)
#pragma unroll
            for (int kk = 0; kk < 2; ++kk) {
                const int row = wm * 128 + (mfh * 4 + mf) * 16 + lr;
                const int g   = kk * 4 + lg;
                af[mf][kk] = *(const bf16x8_t*)&Ab[row * 64 + ((g ^ (row & 7)) << 3)];
            }
    };
    auto dsB0 = [&](const __bf16* Bb) {
#pragma unroll
        for (int kk = 0; kk < 2; ++kk) {
            const int row = wn * 32 + lr;
            const int g   = kk * 4 + lg;
            bf0[0][kk] = *(const bf16x8_t*)&Bb[row * 64 + ((g ^ (row & 7)) << 3)];
        }
    };
    auto dsB1 = [&](const __bf16* Bb) {
#pragma unroll
        for (int kk = 0; kk < 2; ++kk) {
            const int row = wn * 32 + 16 + lr;
            const int g   = kk * 4 + lg;
            bf1[0][kk] = *(const bf16x8_t*)&Bb[row * 64 + ((g ^ (row & 7)) << 3)];
        }
    };
    auto MF0 = [&](int mfh) {
        __builtin_amdgcn_s_setprio(1);
#pragma unroll
        for (int mf = 0; mf < 4; ++mf) {
            const int ai = mfh * 4 + mf;
            acc[ai][0] = __builtin_amdgcn_mfma_f32_16x16x32_bf16(af[mf][0], bf0[0][0], acc[ai][0], 0, 0, 0);
            acc[ai][0] = __builtin_amdgcn_mfma_f32_16x16x32_bf16(af[mf][1], bf0[0][1], acc[ai][0], 0, 0, 0);
        }
        __builtin_amdgcn_s_setprio(0);
    };
    auto MF1 = [&](int mfh) {
        __builtin_amdgcn_s_setprio(1);
#pragma unroll
        for (int mf = 0; mf < 4; ++mf) {
            const int ai = mfh * 4 + mf;
            acc[ai][1] = __builtin_amdgcn_mfma_f32_16x16x32_bf16(af[mf][0], bf1[0][0], acc[ai][1], 0, 0, 0);
            acc[ai][1] = __builtin_amdgcn_mfma_f32_16x16x32_bf16(af[mf][1], bf1[0][1], acc[ai][1], 0, 0, 0);
        }
        __builtin_amdgcn_s_setprio(0);
    };

#define BAR() __builtin_amdgcn_s_barrier()
#define LGK0() asm volatile("s_waitcnt lgkmcnt(0)" ::: "memory")

    stA(0, 0, 0); stA(0, 0, 1); stBlo(0, 0); stBhi(0, 0);
    stBlo(1, 1); stBhi(1, 1);
    asm volatile("s_waitcnt vmcnt(2)" ::: "memory");
    BAR();

    for (int it = 0; it < NI; ++it) {
        const int t1 = 2 * it + 1, t2 = 2 * it + 2, t3 = 2 * it + 3;
        const bool lastit = (it == NI - 1);

        dsA(As[0], 0); dsB0(Bs[0]);
        stA(t1, 1, 0);
        BAR(); LGK0();
        MF0(0);
        BAR();

        dsB1(Bs[0]);
        stA(t1, 1, 1);
        BAR(); LGK0();
        MF1(0);
        BAR();

        dsA(As[0], 1);
        if (!lastit) stBlo(t2, 0);
        BAR(); LGK0();
        MF0(1);
        BAR();

        if (!lastit) stBhi(t2, 0);
        if (lastit) asm volatile("s_waitcnt vmcnt(0)" ::: "memory");
        else        asm volatile("s_waitcnt vmcnt(2)" ::: "memory");
        BAR();
        MF1(1);
        BAR();

        dsA(As[1], 0); dsB0(Bs[1]);
        if (!lastit) stA(t2, 0, 0);
        BAR(); LGK0();
        MF0(0);
        BAR();

        dsB1(Bs[1]);
        if (!lastit) stA(t2, 0, 1);
        BAR(); LGK0();
        MF1(0);
        BAR();

        dsA(As[1], 1);
        if (!lastit) stBlo(t3, 1);
        BAR(); LGK0();
        MF0(1);
        BAR();

        if (!lastit) stBhi(t3, 1);
        if (lastit) asm volatile("s_waitcnt vmcnt(0)" ::: "memory");
        else        asm volatile("s_waitcnt vmcnt(2)" ::: "memory");
        BAR();
        MF1(1);
        BAR();
    }
#undef BAR
#undef LGK0

    if (n0 < 2048) {
        // Q/K region: row-major store, ld=2048
#pragma unroll
        for (int mf = 0; mf < 8; ++mf) {
            const int row0 = m0 + wm * 128 + mf * 16 + cr;
#pragma unroll
            for (int nf = 0; nf < 2; ++nf) {
                const int col = n0 + wn * 32 + nf * 16 + lr;
#pragma unroll
                for (int r = 0; r < 4; ++r)
                    Cqk[(size_t)(row0 + r) * 2048 + col] = (__bf16)acc[mf][nf][r];
            }
        }
    } else {
        // V region: write TRANSPOSED into Vg[(b*16+h)*64+d][2048], packed b64
#pragma unroll
        for (int mf = 0; mf < 8; ++mf) {
            const int row0 = m0 + wm * 128 + mf * 16 + cr;
            const int bb   = row0 >> 11;
            const int tt   = row0 & 2047;
#pragma unroll
            for (int nf = 0; nf < 2; ++nf) {
                const int c3 = n0 + wn * 32 + nf * 16 + lr - 2048;
                const int hh = c3 >> 6, dd = c3 & 63;
                bf16x4_t pv;
#pragma unroll
                for (int r = 0; r < 4; ++r) pv[r] = (__bf16)acc[mf][nf][r];
                *(bf16x4_t*)&Vg[((size_t)(bb * 16 + hh) * 64 + dd) * 2048 + tt] = pv;
            }
        }
    }
}

// GEMM2: out = y @ w_proj^T, fp32 output (R17, proven). grid 256 = 1 CU-wave.
__global__ __launch_bounds__(512, 2) void gemm2_m201(const __bf16* __restrict__ A,
                                                     const __bf16* __restrict__ Bt,
                                                     float* __restrict__ C,
                                                     int M, int N, int K) {
    __shared__ __bf16 As[2][256 * 64];
    __shared__ __bf16 Bs[2][128 * 64];

    const int tid  = threadIdx.x;
    const int lane = tid & 63;
    const int wid  = tid >> 6;
    const int wm   = wid >> 2;
    const int wn   = wid & 3;

    int fl = blockIdx.x;
    fl = (fl & 7) * (gridDim.x >> 3) + (fl >> 3);
    const int m0 = (fl >> 3) * 256;
    const int n0 = (fl & 7) * 128;

    const int lr = lane & 15;
    const int lg = lane >> 4;
    const int cr = lg * 4;
    const int srow = lane >> 3;
    const int gcol = (((lane & 7) ^ srow) << 3);

    f32x4_t acc[8][2];
#pragma unroll
    for (int i = 0; i < 8; ++i)
#pragma unroll
        for (int j = 0; j < 2; ++j)
            acc[i][j] = (f32x4_t){0.f, 0.f, 0.f, 0.f};

    const int NT = K >> 6;
    const int NI = NT >> 1;

    bf16x8_t af[4][2], bf0[1][2], bf1[1][2];

    auto stA = [&](int kt, int buf, int half) {
        const __bf16* Ab = A + (size_t)m0 * K + (size_t)kt * 64;
        const int s0 = half * 16 + wid, s1 = s0 + 8;
        gload_lds16(Ab + (size_t)(s0 * 8 + srow) * K + gcol, &As[buf][s0 * 512]);
        gload_lds16(Ab + (size_t)(s1 * 8 + srow) * K + gcol, &As[buf][s1 * 512]);
    };
    auto stBlo = [&](int kt, int buf) {
        const __bf16* Bb = Bt + (size_t)n0 * K + (size_t)kt * 64;
        gload_lds16(Bb + (size_t)(wid * 8 + srow) * K + gcol, &Bs[buf][wid * 512]);
    };
    auto stBhi = [&](int kt, int buf) {
        const __bf16* Bb = Bt + (size_t)n0 * K + (size_t)kt * 64;
        gload_lds16(Bb + (size_t)((wid + 8) * 8 + srow) * K + gcol, &Bs[buf][(wid + 8) * 512]);
    };
    auto dsA = [&](const __bf16* Ab, int mfh) {
#pragma unroll
        for (int mf = 0; mf < 4; ++mf)
#pragma unroll
            for (int kk = 0; kk < 2; ++kk) {
                const int row = wm * 128 + (mfh * 4 + mf) * 16 + lr;
                const int g   = kk * 4 + lg;
                af[mf][kk] = *(const bf16x8_t*)&Ab[row * 64 + ((g ^ (row & 7)) << 3)];
            }
    };
    auto dsB0 = [&](const __bf16* Bb) {
#pragma unroll
        for (int kk = 0; kk < 2; ++kk) {
            const int row = wn * 32 + lr;
            const int g   = kk * 4 + lg;
            bf0[0][kk] = *(const bf16x8_t*)&Bb[row * 64 + ((g ^ (row & 7)) << 3)];
        }
    };
    auto dsB1 = [&](const __bf16* Bb) {
#pragma unroll
        for (int kk = 0; kk < 2; ++kk) {
            const int row = wn * 32 + 16 + lr;
            const int g   = kk * 4 + lg;
            bf1[0][kk] = *(const bf16x8_t*)&Bb[row * 64 + ((g ^ (row & 7)) << 3)];
        }
    };
    auto MF0 = [&](int mfh) {
        __builtin_amdgcn_s_setprio(1);
#pragma unroll
        for (int mf = 0; mf < 4; ++mf) {
            const int ai = mfh * 4 + mf;
            acc[ai][0] = __builtin_amdgcn_mfma_f32_16x16x32_bf16(af[mf][0], bf0[0][0], acc[ai][0], 0, 0, 0);
            acc[ai][0] = __builtin_amdgcn_mfma_f32_16x16x32_bf16(af[mf][1], bf0[0][1], acc[ai][0], 0, 0, 0);
        }
        __builtin_amdgcn_s_setprio(0);
    };
    auto MF1 = [&](int mfh) {
        __builtin_amdgcn_s_setprio(1);
#pragma unroll
        for (int mf = 0; mf < 4; ++mf) {
            const int ai = mfh * 4 + mf;
            acc[ai][1] = __builtin_amdgcn_mfma_f32_16x16x32_bf16(af[mf][0], bf1[0][0], acc[ai][1], 0, 0, 0);
            acc[ai][1] = __builtin_amdgcn_mfma_f32_16x16x32_bf16(af[mf][1], bf1[0][1], acc[ai][1], 0, 0, 0);
        }
        __builtin_amdgcn_s_setprio(0);
    };

#define BAR() __builtin_amdgcn_s_barrier()
#define LGK0() asm volatile("s_waitcnt lgkmcnt(0)" ::: "memory")

    stA(0, 0, 0); stA(0, 0, 1); stBlo(0, 0); stBhi(0, 0);
    stBlo(1, 1); stBhi(1, 1);
    asm volatile("s_waitcnt vmcnt(2)" ::: "memory");
    BAR();

    for (int it = 0; it < NI; ++it) {
        const int t1 = 2 * it + 1, t2 = 2 * it + 2, t3 = 2 * it + 3;
        const bool lastit = (it == NI - 1);

        dsA(As[0], 0); dsB0(Bs[0]);
        stA(t1, 1, 0);
        BAR(); LGK0();
        MF0(0);
        BAR();

        dsB1(Bs[0]);
        stA(t1, 1, 1);
        BAR(); LGK0();
        MF1(0);
        BAR();

        dsA(As[0], 1);
        if (!lastit) stBlo(t2, 0);
        BAR(); LGK0();
        MF0(1);
        BAR();

        if (!lastit) stBhi(t2, 0);
        if (lastit) asm volatile("s_waitcnt vmcnt(0)" ::: "memory");
        else        asm volatile("s_waitcnt vmcnt(2)" ::: "memory");
        BAR();
        MF1(1);
        BAR();

        dsA(As[1], 0); dsB0(Bs[1]);
        if (!lastit) stA(t2, 0, 0);
        BAR(); LGK0();
        MF0(0);
        BAR();

        dsB1(Bs[1]);
        if (!lastit) stA(t2, 0, 1);
        BAR(); LGK0();
        MF1(0);
        BAR();

        dsA(As[1], 1);
        if (!lastit) stBlo(t3, 1);
        BAR(); LGK0();
        MF0(1);
        BAR();

        if (!lastit) stBhi(t3, 1);
        if (lastit) asm volatile("s_waitcnt vmcnt(0)" ::: "memory");
        else        asm volatile("s_waitcnt vmcnt(2)" ::: "memory");
        BAR();
        MF1(1);
        BAR();
    }
#undef BAR
#undef LGK0

#pragma unroll
    for (int mf = 0; mf < 8; ++mf) {
        const int row0 = m0 + wm * 128 + mf * 16 + cr;
#pragma unroll
        for (int nf = 0; nf < 2; ++nf) {
            const int col = n0 + wn * 32 + nf * 16 + lr;
#pragma unroll
            for (int r = 0; r < 4; ++r)
                C[(size_t)(row0 + r) * 1024 + col] = acc[mf][nf][r];
        }
    }
}

// ---------------- flash attention (causal), v12 (R16 best) ----------------
__global__ __launch_bounds__(256, 2) void attn_kernel(const __bf16* __restrict__ qkv,  // [8192][2048] Q|K
                                                      const __bf16* __restrict__ Vg,   // [(b*16+h)*64+d][2048]
                                                      __bf16* __restrict__ y) {
    const int T = 2048, LD = 2048;
    const int orig = blockIdx.x;
    const int bidx = ((orig & 7) << 6) + (orig >> 3);   // XCD swizzle (512 % 8 == 0)
    const int pair = bidx & 7;
    const int h    = (bidx >> 3) & 15;
    const int b    = bidx >> 7;

    __shared__ __bf16 Ks[2][128 * 64];
    __shared__ __bf16 Vt[2][64 * 128];

    const int tid  = threadIdx.x;
    const int lane = tid & 63;
    const int w    = tid >> 6;
    const int l31  = lane & 31;
    const int hi   = lane >> 5;

    const __bf16* qg  = qkv + (size_t)b * T * LD + h * 64;
    const __bf16* kg  = qg + 1024;
    const __bf16* Vgb = Vg + (size_t)(b * 16 + h) * 64 * 2048;

    const float CE    = 0.125f * 1.44269504f;
    const float DEFER = 8.0f;

    const int kc = tid & 7;
    const int kr8 = tid >> 3;
    const int kslot = (kc ^ (kr8 & 7)) << 3;
    const int vc = tid & 15;
    const int vd8 = tid >> 4;
    const int vslot = (vc ^ (vd8 & 7)) << 3;

    bf16x8_t ones8;
#pragma unroll
    for (int j = 0; j < 8; ++j) ones8[j] = (__bf16)1.0f;

    for (int pass = 0; pass < 2; ++pass) {
        const int qs  = pass ? 15 - pair : pair;
        const int qt0 = qs * 128;
        const int nt  = qs + 1;
        const int qgl = qt0 + w * 32 + l31;

        bf16x8_t qreg[4];
#pragma unroll
        for (int ks = 0; ks < 4; ++ks) {
            bf16x8_t qr = *(const bf16x8_t*)&qg[(size_t)qgl * LD + ks * 16 + 8 * hi];
            union { unsigned u[4]; bf16x8_t v; } pq;
#pragma unroll
            for (int j = 0; j < 4; ++j)
                pq.u[j] = pk_bf16((float)qr[2 * j] * CE, (float)qr[2 * j + 1] * CE);
            qreg[ks] = pq.v;
        }

        bf16x8_t kreg[4], vreg[4];
#pragma unroll
        for (int jj = 0; jj < 4; ++jj)
            kreg[jj] = *(const bf16x8_t*)&kg[(size_t)(kr8 + 32 * jj) * LD + kc * 8];
#pragma unroll
        for (int jj = 0; jj < 4; ++jj)
            vreg[jj] = *(const bf16x8_t*)&Vgb[(size_t)(vd8 + 16 * jj) * 2048 + vc * 8];

        f32x16_t o0 = (f32x16_t)(0.f), o1 = (f32x16_t)(0.f);
        f32x16_t o2 = (f32x16_t)(0.f);
        float m_r = -3.0e38f;

        __syncthreads();   // pass boundary

        for (int t = 0; t < nt; ++t) {
            __bf16* Kb = Ks[t & 1];
            __bf16* Vb = Vt[t & 1];

#pragma unroll
            for (int jj = 0; jj < 4; ++jj)
                *(bf16x8_t*)&Kb[(kr8 + 32 * jj) * 64 + kslot] = kreg[jj];
#pragma unroll
            for (int jj = 0; jj < 4; ++jj)
                *(bf16x8_t*)&Vb[(vd8 + 16 * jj) * 128 + vslot] = vreg[jj];

            __syncthreads();

            if (t + 1 < nt) {
                const size_t kb0 = (size_t)(t + 1) * 128;
#pragma unroll
                for (int jj = 0; jj < 4; ++jj)
                    kreg[jj] = *(const bf16x8_t*)&kg[(kb0 + kr8 + 32 * jj) * LD + kc * 8];
#pragma unroll
                for (int jj = 0; jj < 4; ++jj)
                    vreg[jj] = *(const bf16x8_t*)&Vgb[(size_t)(vd8 + 16 * jj) * 2048 + kb0 + vc * 8];
            }

            f32x16_t s[4];
            __builtin_amdgcn_s_setprio(1);
#pragma unroll
            for (int kb = 0; kb < 4; ++kb) {
                const int key = kb * 32 + l31;
                const int sw7 = key & 7;
                s[kb] = (f32x16_t)(0.f);
#pragma unroll
                for (int ks = 0; ks < 4; ++ks) {
                    bf16x8_t kf = *(const bf16x8_t*)&Kb[key * 64 + (((2 * ks + hi) ^ sw7) << 3)];
                    s[kb] = __builtin_amdgcn_mfma_f32_32x32x16_bf16(kf, qreg[ks], s[kb], 0, 0, 0);
                }
            }
            __builtin_amdgcn_s_setprio(0);

            if (t == nt - 1) {
                const int ql = w * 32 + l31;
#pragma unroll
                for (int kb = 0; kb < 4; ++kb)
#pragma unroll
                    for (int r = 0; r < 16; ++r) {
                        const int key = kb * 32 + (r & 3) + 8 * (r >> 2) + 4 * hi;
                        if (key > ql) s[kb][r] = -1.0e30f;
                    }
            }

            float pm = -3.0e38f;
#pragma unroll
            for (int kb = 0; kb < 4; ++kb) {
                float a = fmaxf(fmaxf(s[kb][0], s[kb][1]), s[kb][2]);
                a = fmaxf(fmaxf(a, s[kb][3]), s[kb][4]);
                a = fmaxf(fmaxf(a, s[kb][5]), s[kb][6]);
                a = fmaxf(fmaxf(a, s[kb][7]), s[kb][8]);
                a = fmaxf(fmaxf(a, s[kb][9]), s[kb][10]);
                a = fmaxf(fmaxf(a, s[kb][11]), s[kb][12]);
                a = fmaxf(fmaxf(a, s[kb][13]), s[kb][14]);
                a = fmaxf(a, s[kb][15]);
                pm = fmaxf(pm, a);
            }

            if (!__all(pm <= m_r + DEFER)) {
                pm = fmaxf(pm, __shfl_xor(pm, 32));
                const float mn    = fmaxf(m_r, pm);
                const float alpha = exp2f(m_r - mn);
                o2[0] *= alpha;
#pragma unroll
                for (int r = 0; r < 16; ++r) { o0[r] *= alpha; o1[r] *= alpha; }
                m_r = mn;
            }
            const float mr = m_r;

#pragma unroll
            for (int kb = 0; kb < 4; ++kb)
#pragma unroll
                for (int r = 0; r < 16; ++r)
                    s[kb][r] = exp2f(s[kb][r] - mr);

            __builtin_amdgcn_s_setprio(1);
#pragma unroll
            for (int ks = 0; ks < 8; ++ks) {
                const int kb = ks >> 1;
                const int rb = 8 * (ks & 1);
                unsigned L0 = pk_bf16(s[kb][rb + 0], s[kb][rb + 1]);
                unsigned L1 = pk_bf16(s[kb][rb + 2], s[kb][rb + 3]);
                unsigned H0 = pk_bf16(s[kb][rb + 4], s[kb][rb + 5]);
                unsigned H1 = pk_bf16(s[kb][rb + 6], s[kb][rb + 7]);
                asm("v_permlane32_swap_b32 %0, %1" : "+v"(L0), "+v"(H0));
                asm("v_permlane32_swap_b32 %0, %1" : "+v"(L1), "+v"(H1));
                union { unsigned u[4]; bf16x8_t v; } uf;
                uf.u[0] = L0; uf.u[1] = L1; uf.u[2] = H0; uf.u[3] = H1;
                const int gv = 2 * ks + hi;
                {
                    const int d = l31;
                    bf16x8_t vf = *(const bf16x8_t*)&Vb[d * 128 + ((gv ^ (d & 7)) << 3)];
                    o0 = __builtin_amdgcn_mfma_f32_32x32x16_bf16(vf, uf.v, o0, 0, 0, 0);
                }
                {
                    const int d = 32 + l31;
                    bf16x8_t vf = *(const bf16x8_t*)&Vb[d * 128 + ((gv ^ (d & 7)) << 3)];
                    o1 = __builtin_amdgcn_mfma_f32_32x32x16_bf16(vf, uf.v, o1, 0, 0, 0);
                }
                o2 = __builtin_amdgcn_mfma_f32_32x32x16_bf16(ones8, uf.v, o2, 0, 0, 0);
            }
            __builtin_amdgcn_s_setprio(0);
        }

        const float inv = 1.0f / o2[0];
        __bf16* yrow = y + (size_t)(b * T + qgl) * 1024 + h * 64;
#pragma unroll
        for (int tq = 0; tq < 4; ++tq) {
            bf16x4_t ov0, ov1;
#pragma unroll
            for (int u = 0; u < 4; ++u) {
                ov0[u] = (__bf16)(o0[tq * 4 + u] * inv);
                ov1[u] = (__bf16)(o1[tq * 4 + u] * inv);
            }
            const int dl = 8 * tq + 4 * hi;
            *(bf16x4_t*)&yrow[dl]      = ov0;
            *(bf16x4_t*)&yrow[32 + dl] = ov1;
        }
    }
}

// ---------------- launch ----------------
extern "C" void kernel_launch(void* const* d_in, const int* in_sizes, int n_in,
                              void* d_out, int out_size, void* d_ws, size_t ws_size,
                              hipStream_t stream) {
    const float* x      = (const float*)d_in[0];
    const float* w_attn = (const float*)d_in[1];
    const float* w_proj = (const float*)d_in[2];
    float* out = (float*)d_out;

    char* ws = (char*)d_ws;
    __bf16* xb   = (__bf16*)(ws);                      // 8192*1024      = 16 MB
    __bf16* wab  = (__bf16*)(ws + 16777216);           // 3072*1024      = 6 MB
    __bf16* wpb  = (__bf16*)(ws + 23068672);           // 1024*1024      = 2 MB
    __bf16* qkvb = (__bf16*)(ws + 25165824);           // 8192*2048 Q|K  = 32 MB
    __bf16* yb   = (__bf16*)(ws + 58720256);           // 8192*1024      = 16 MB
    __bf16* Vg   = (__bf16*)(ws + 75497472);           // 64*64*2048     = 16 MB

    f2bf3_kernel<<<12288, 256, 0, stream>>>(x, w_attn, w_proj, xb, wab, wpb);

    // qkv: Q/K -> qkvb [8192][2048]; V -> Vg transposed  (256x128 8-phase, 768 blocks)
    gemm1_m201<<<768, 512, 0, stream>>>(xb, wab, qkvb, Vg, 8192, 3072, 1024);

    // flash attention -> yb [8192, 1024]
    attn_kernel<<<512, 256, 0, stream>>>(qkvb, Vg, yb);

    // out = yb @ w_proj^T  [8192, 1024] fp32  (256x128 8-phase, 256 blocks)
    gemm2_m201<<<256, 512, 0, stream>>>(yb, wpb, out, 8192, 1024, 1024);
}

// Round 19
// 175.009 us; speedup vs baseline: 1.0054x; 1.0054x over previous
//
#include <hip/hip_runtime.h>
#include <hip/hip_bf16.h>

typedef __bf16 bf16x8_t __attribute__((ext_vector_type(8)));
typedef __bf16 bf16x4_t __attribute__((ext_vector_type(4)));
typedef float f32x4_t __attribute__((ext_vector_type(4)));
typedef float f32x16_t __attribute__((ext_vector_type(16)));

__device__ __forceinline__ void gload_lds16(const void* g, void* l) {
    __builtin_amdgcn_global_load_lds((const __attribute__((address_space(1))) void*)g,
                                     (__attribute__((address_space(3))) void*)l, 16, 0, 0);
}

__device__ __forceinline__ unsigned pk_bf16(float a, float b) {
    unsigned r;
    asm("v_cvt_pk_bf16_f32 %0, %1, %2" : "=v"(r) : "v"(a), "v"(b));
    return r;
}

// ---------------- fused fp32 -> bf16 conversion (x, w_attn, w_proj) ----------------
__global__ void f2bf3_kernel(const float* __restrict__ x, const float* __restrict__ wa,
                             const float* __restrict__ wp, __bf16* __restrict__ xb,
                             __bf16* __restrict__ wab, __bf16* __restrict__ wpb) {
    int i = blockIdx.x * blockDim.x + threadIdx.x;   // float4 index, total 3145728
    const float* in; __bf16* out; int off;
    if (i < 2097152)      { in = x;  out = xb;  off = i; }
    else if (i < 2883584) { in = wa; out = wab; off = i - 2097152; }
    else                  { in = wp; out = wpb; off = i - 2883584; }
    float4 v = *(const float4*)(in + off * 4);
    bf16x4_t o;
    o[0] = (__bf16)v.x; o[1] = (__bf16)v.y; o[2] = (__bf16)v.z; o[3] = (__bf16)v.w;
    *(bf16x4_t*)(out + off * 4) = o;
}

// ---------------- GEMM1: 256x192 8-phase, BK=64, 512 blocks (R15 proven, m-minor map) ----------------
__global__ __launch_bounds__(512, 2) void gemm1_m201(const __bf16* __restrict__ A,
                                                     const __bf16* __restrict__ Bt,
                                                     __bf16* __restrict__ Cqk,
                                                     __bf16* __restrict__ Vg,
                                                     int M, int N, int K) {
    __shared__ __bf16 As[2][256 * 64];
    __shared__ __bf16 Bs[2][192 * 64];

    const int tid  = threadIdx.x;
    const int lane = tid & 63;
    const int wid  = tid >> 6;
    const int wm   = wid >> 2;
    const int wn   = wid & 3;

    int fl = blockIdx.x;
    fl = (fl & 7) * (gridDim.x >> 3) + (fl >> 3);   // 512 % 8 == 0 -> bijective
    // m-minor: each XCD chunk (64 fl) spans only 2 N-panels -> B L2-resident
    const int m0 = (fl & 31) * 256;
    const int n0 = (fl >> 5) * 192;

    const int lr = lane & 15;
    const int lg = lane >> 4;
    const int cr = lg * 4;
    const int srow = lane >> 3;
    const int gcol = (((lane & 7) ^ srow) << 3);

    f32x4_t acc[8][3];
#pragma unroll
    for (int i = 0; i < 8; ++i)
#pragma unroll
        for (int j = 0; j < 3; ++j)
            acc[i][j] = (f32x4_t){0.f, 0.f, 0.f, 0.f};

    const int NT = K >> 6;
    const int NI = NT >> 1;

    bf16x8_t af[4][2], bf0[2][2], bf1[1][2];

    auto stA = [&](int kt, int buf, int half) {
        const __bf16* Ab = A + (size_t)m0 * K + (size_t)kt * 64;
        const int s0 = half * 16 + wid, s1 = s0 + 8;
        gload_lds16(Ab + (size_t)(s0 * 8 + srow) * K + gcol, &As[buf][s0 * 512]);
        gload_lds16(Ab + (size_t)(s1 * 8 + srow) * K + gcol, &As[buf][s1 * 512]);
    };
    auto stBlo = [&](int kt, int buf) {
        const __bf16* Bb = Bt + (size_t)n0 * K + (size_t)kt * 64;
        gload_lds16(Bb + (size_t)(wid * 8 + srow) * K + gcol, &Bs[buf][wid * 512]);
        gload_lds16(Bb + (size_t)((wid + 8) * 8 + srow) * K + gcol, &Bs[buf][(wid + 8) * 512]);
    };
    auto stBhi = [&](int kt, int buf) {
        const __bf16* Bb = Bt + (size_t)n0 * K + (size_t)kt * 64;
        gload_lds16(Bb + (size_t)((wid + 16) * 8 + srow) * K + gcol, &Bs[buf][(wid + 16) * 512]);
    };
    auto dsA = [&](const __bf16* Ab, int mfh) {
#pragma unroll
        for (int mf = 0; mf < 4; ++mf)
#pragma unroll
            for (int kk = 0; kk < 2; ++kk) {
                const int row = wm * 128 + (mfh * 4 + mf) * 16 + lr;
                const int g   = kk * 4 + lg;
                af[mf][kk] = *(const bf16x8_t*)&Ab[row * 64 + ((g ^ (row & 7)) << 3)];
            }
    };
    auto dsB0 = [&](const __bf16* Bb) {
#pragma unroll
        for (int nfp = 0; nfp < 2; ++nfp)
#pragma unroll
            for (int kk = 0; kk < 2; ++kk) {
                const int row = wn * 48 + nfp * 16 + lr;
                const int g   = kk * 4 + lg;
                bf0[nfp][kk] = *(const bf16x8_t*)&Bb[row * 64 + ((g ^ (row & 7)) << 3)];
            }
    };
    auto dsB1 = [&](const __bf16* Bb) {
#pragma unroll
        for (int kk = 0; kk < 2; ++kk) {
            const int row = wn * 48 + 2 * 16 + lr;
            const int g   = kk * 4 + lg;
            bf1[0][kk] = *(const bf16x8_t*)&Bb[row * 64 + ((g ^ (row & 7)) << 3)];
        }
    };
    auto MF0 = [&](int mfh) {
        __builtin_amdgcn_s_setprio(1);
#pragma unroll
        for (int mf = 0; mf < 4; ++mf)
#pragma unroll
            for (int nfp = 0; nfp < 2; ++nfp) {
                const int ai = mfh * 4 + mf;
                acc[ai][nfp] = __builtin_amdgcn_mfma_f32_16x16x32_bf16(af[mf][0], bf0[nfp][0], acc[ai][nfp], 0, 0, 0);
                acc[ai][nfp] = __builtin_amdgcn_mfma_f32_16x16x32_bf16(af[mf][1], bf0[nfp][1], acc[ai][nfp], 0, 0, 0);
            }
        __builtin_amdgcn_s_setprio(0);
    };
    auto MF1 = [&](int mfh) {
        __builtin_amdgcn_s_setprio(1);
#pragma unroll
        for (int mf = 0; mf < 4; ++mf) {
            const int ai = mfh * 4 + mf;
            acc[ai][2] = __builtin_amdgcn_mfma_f32_16x16x32_bf16(af[mf][0], bf1[0][0], acc[ai][2], 0, 0, 0);
            acc[ai][2] = __builtin_amdgcn_mfma_f32_16x16x32_bf16(af[mf][1], bf1[0][1], acc[ai][2], 0, 0, 0);
        }
        __builtin_amdgcn_s_setprio(0);
    };

#define BAR() __builtin_amdgcn_s_barrier()
#define LGK0() asm volatile("s_waitcnt lgkmcnt(0)" ::: "memory")

    stA(0, 0, 0); stA(0, 0, 1); stBlo(0, 0); stBhi(0, 0);
    stBlo(1, 1); stBhi(1, 1);
    asm volatile("s_waitcnt vmcnt(3)" ::: "memory");
    BAR();

    for (int it = 0; it < NI; ++it) {
        const int t1 = 2 * it + 1, t2 = 2 * it + 2, t3 = 2 * it + 3;
        const bool lastit = (it == NI - 1);

        dsA(As[0], 0); dsB0(Bs[0]);
        stA(t1, 1, 0);
        BAR(); LGK0();
        MF0(0);
        BAR();

        dsB1(Bs[0]);
        stA(t1, 1, 1);
        BAR(); LGK0();
        MF1(0);
        BAR();

        dsA(As[0], 1);
        if (!lastit) stBlo(t2, 0);
        BAR(); LGK0();
        MF0(1);
        BAR();

        if (!lastit) stBhi(t2, 0);
        if (lastit) asm volatile("s_waitcnt vmcnt(0)" ::: "memory");
        else        asm volatile("s_waitcnt vmcnt(3)" ::: "memory");
        BAR();
        MF1(1);
        BAR();

        dsA(As[1], 0); dsB0(Bs[1]);
        if (!lastit) stA(t2, 0, 0);
        BAR(); LGK0();
        MF0(0);
        BAR();

        dsB1(Bs[1]);
        if (!lastit) stA(t2, 0, 1);
        BAR(); LGK0();
        MF1(0);
        BAR();

        dsA(As[1], 1);
        if (!lastit) stBlo(t3, 1);
        BAR(); LGK0();
        MF0(1);
        BAR();

        if (!lastit) stBhi(t3, 1);
        if (lastit) asm volatile("s_waitcnt vmcnt(0)" ::: "memory");
        else        asm volatile("s_waitcnt vmcnt(3)" ::: "memory");
        BAR();
        MF1(1);
        BAR();
    }
#undef BAR
#undef LGK0

#pragma unroll
    for (int mf = 0; mf < 8; ++mf) {
        const int row0 = m0 + wm * 128 + mf * 16 + cr;
        const int bb   = row0 >> 11;
        const int tt   = row0 & 2047;
#pragma unroll
        for (int nf = 0; nf < 3; ++nf) {
            const int colb = n0 + wn * 48 + nf * 16;
            if (colb < 2048) {
#pragma unroll
                for (int r = 0; r < 4; ++r)
                    Cqk[(size_t)(row0 + r) * 2048 + colb + lr] = (__bf16)acc[mf][nf][r];
            } else {
                const int c3 = colb + lr - 2048;
                const int hh = c3 >> 6, dd = c3 & 63;
                bf16x4_t pv;
#pragma unroll
                for (int r = 0; r < 4; ++r) pv[r] = (__bf16)acc[mf][nf][r];
                *(bf16x4_t*)&Vg[((size_t)(bb * 16 + hh) * 64 + dd) * 2048 + tt] = pv;
            }
        }
    }
}

// ---------------- GEMM2: 256x128 8-phase, BK=64, 256 blocks (R17 proven) ----------------
__global__ __launch_bounds__(512, 2) void gemm2_m201(const __bf16* __restrict__ A,
                                                     const __bf16* __restrict__ Bt,
                                                     float* __restrict__ C,
                                                     int M, int N, int K) {
    __shared__ __bf16 As[2][256 * 64];
    __shared__ __bf16 Bs[2][128 * 64];

    const int tid  = threadIdx.x;
    const int lane = tid & 63;
    const int wid  = tid >> 6;
    const int wm   = wid >> 2;
    const int wn   = wid & 3;

    int fl = blockIdx.x;
    fl = (fl & 7) * (gridDim.x >> 3) + (fl >> 3);
    const int m0 = (fl >> 3) * 256;
    const int n0 = (fl & 7) * 128;

    const int lr = lane & 15;
    const int lg = lane >> 4;
    const int cr = lg * 4;
    const int srow = lane >> 3;
    const int gcol = (((lane & 7) ^ srow) << 3);

    f32x4_t acc[8][2];
#pragma unroll
    for (int i = 0; i < 8; ++i)
#pragma unroll
        for (int j = 0; j < 2; ++j)
            acc[i][j] = (f32x4_t){0.f, 0.f, 0.f, 0.f};

    const int NT = K >> 6;
    const int NI = NT >> 1;

    bf16x8_t af[4][2], bf0[1][2], bf1[1][2];

    auto stA = [&](int kt, int buf, int half) {
        const __bf16* Ab = A + (size_t)m0 * K + (size_t)kt * 64;
        const int s0 = half * 16 + wid, s1 = s0 + 8;
        gload_lds16(Ab + (size_t)(s0 * 8 + srow) * K + gcol, &As[buf][s0 * 512]);
        gload_lds16(Ab + (size_t)(s1 * 8 + srow) * K + gcol, &As[buf][s1 * 512]);
    };
    auto stBlo = [&](int kt, int buf) {
        const __bf16* Bb = Bt + (size_t)n0 * K + (size_t)kt * 64;
        gload_lds16(Bb + (size_t)(wid * 8 + srow) * K + gcol, &Bs[buf][wid * 512]);
    };
    auto stBhi = [&](int kt, int buf) {
        const __bf16* Bb = Bt + (size_t)n0 * K + (size_t)kt * 64;
        gload_lds16(Bb + (size_t)((wid + 8) * 8 + srow) * K + gcol, &Bs[buf][(wid + 8) * 512]);
    };
    auto dsA = [&](const __bf16* Ab, int mfh) {
#pragma unroll
        for (int mf = 0; mf < 4; ++mf)
#pragma unroll
            for (int kk = 0; kk < 2; ++kk) {
                const int row = wm * 128 + (mfh * 4 + mf) * 16 + lr;
                const int g   = kk * 4 + lg;
                af[mf][kk] = *(const bf16x8_t*)&Ab[row * 64 + ((g ^ (row & 7)) << 3)];
            }
    };
    auto dsB0 = [&](const __bf16* Bb) {
#pragma unroll
        for (int kk = 0; kk < 2; ++kk) {
            const int row = wn * 32 + lr;
            const int g   = kk * 4 + lg;
            bf0[0][kk] = *(const bf16x8_t*)&Bb[row * 64 + ((g ^ (row & 7)) << 3)];
        }
    };
    auto dsB1 = [&](const __bf16* Bb) {
#pragma unroll
        for (int kk = 0; kk < 2; ++kk) {
            const int row = wn * 32 + 16 + lr;
            const int g   = kk * 4 + lg;
            bf1[0][kk] = *(const bf16x8_t*)&Bb[row * 64 + ((g ^ (row & 7)) << 3)];
        }
    };
    auto MF0 = [&](int mfh) {
        __builtin_amdgcn_s_setprio(1);
#pragma unroll
        for (int mf = 0; mf < 4; ++mf) {
            const int ai = mfh * 4 + mf;
            acc[ai][0] = __builtin_amdgcn_mfma_f32_16x16x32_bf16(af[mf][0], bf0[0][0], acc[ai][0], 0, 0, 0);
            acc[ai][0] = __builtin_amdgcn_mfma_f32_16x16x32_bf16(af[mf][1], bf0[0][1], acc[ai][0], 0, 0, 0);
        }
        __builtin_amdgcn_s_setprio(0);
    };
    auto MF1 = [&](int mfh) {
        __builtin_amdgcn_s_setprio(1);
#pragma unroll
        for (int mf = 0; mf < 4; ++mf) {
            const int ai = mfh * 4 + mf;
            acc[ai][1] = __builtin_amdgcn_mfma_f32_16x16x32_bf16(af[mf][0], bf1[0][0], acc[ai][1], 0, 0, 0);
            acc[ai][1] = __builtin_amdgcn_mfma_f32_16x16x32_bf16(af[mf][1], bf1[0][1], acc[ai][1], 0, 0, 0);
        }
        __builtin_amdgcn_s_setprio(0);
    };

#define BAR() __builtin_amdgcn_s_barrier()
#define LGK0() asm volatile("s_waitcnt lgkmcnt(0)" ::: "memory")

    stA(0, 0, 0); stA(0, 0, 1); stBlo(0, 0); stBhi(0, 0);
    stBlo(1, 1); stBhi(1, 1);
    asm volatile("s_waitcnt vmcnt(2)" ::: "memory");
    BAR();

    for (int it = 0; it < NI; ++it) {
        const int t1 = 2 * it + 1, t2 = 2 * it + 2, t3 = 2 * it + 3;
        const bool lastit = (it == NI - 1);

        dsA(As[0], 0); dsB0(Bs[0]);
        stA(t1, 1, 0);
        BAR(); LGK0();
        MF0(0);
        BAR();

        dsB1(Bs[0]);
        stA(t1, 1, 1);
        BAR(); LGK0();
        MF1(0);
        BAR();

        dsA(As[0], 1);
        if (!lastit) stBlo(t2, 0);
        BAR(); LGK0();
        MF0(1);
        BAR();

        if (!lastit) stBhi(t2, 0);
        if (lastit) asm volatile("s_waitcnt vmcnt(0)" ::: "memory");
        else        asm volatile("s_waitcnt vmcnt(2)" ::: "memory");
        BAR();
        MF1(1);
        BAR();

        dsA(As[1], 0); dsB0(Bs[1]);
        if (!lastit) stA(t2, 0, 0);
        BAR(); LGK0();
        MF0(0);
        BAR();

        dsB1(Bs[1]);
        if (!lastit) stA(t2, 0, 1);
        BAR(); LGK0();
        MF1(0);
        BAR();

        dsA(As[1], 1);
        if (!lastit) stBlo(t3, 1);
        BAR(); LGK0();
        MF0(1);
        BAR();

        if (!lastit) stBhi(t3, 1);
        if (lastit) asm volatile("s_waitcnt vmcnt(0)" ::: "memory");
        else        asm volatile("s_waitcnt vmcnt(2)" ::: "memory");
        BAR();
        MF1(1);
        BAR();
    }
#undef BAR
#undef LGK0

#pragma unroll
    for (int mf = 0; mf < 8; ++mf) {
        const int row0 = m0 + wm * 128 + mf * 16 + cr;
#pragma unroll
        for (int nf = 0; nf < 2; ++nf) {
            const int col = n0 + wn * 32 + nf * 16 + lr;
#pragma unroll
            for (int r = 0; r < 4; ++r)
                C[(size_t)(row0 + r) * 1024 + col] = acc[mf][nf][r];
        }
    }
}

// ---------------- flash attention (causal), v12 (R16/R17 best) ----------------
__global__ __launch_bounds__(256, 2) void attn_kernel(const __bf16* __restrict__ qkv,  // [8192][2048] Q|K
                                                      const __bf16* __restrict__ Vg,   // [(b*16+h)*64+d][2048]
                                                      __bf16* __restrict__ y) {
    const int T = 2048, LD = 2048;
    const int orig = blockIdx.x;
    const int bidx = ((orig & 7) << 6) + (orig >> 3);   // XCD swizzle (512 % 8 == 0)
    const int pair = bidx & 7;
    const int h    = (bidx >> 3) & 15;
    const int b    = bidx >> 7;

    __shared__ __bf16 Ks[2][128 * 64];
    __shared__ __bf16 Vt[2][64 * 128];

    const int tid  = threadIdx.x;
    const int lane = tid & 63;
    const int w    = tid >> 6;
    const int l31  = lane & 31;
    const int hi   = lane >> 5;

    const __bf16* qg  = qkv + (size_t)b * T * LD + h * 64;
    const __bf16* kg  = qg + 1024;
    const __bf16* Vgb = Vg + (size_t)(b * 16 + h) * 64 * 2048;

    const float CE    = 0.125f * 1.44269504f;
    const float DEFER = 8.0f;

    const int kc = tid & 7;
    const int kr8 = tid >> 3;
    const int kslot = (kc ^ (kr8 & 7)) << 3;
    const int vc = tid & 15;
    const int vd8 = tid >> 4;
    const int vslot = (vc ^ (vd8 & 7)) << 3;

    bf16x8_t ones8;
#pragma unroll
    for (int j = 0; j < 8; ++j) ones8[j] = (__bf16)1.0f;

    for (int pass = 0; pass < 2; ++pass) {
        const int qs  = pass ? 15 - pair : pair;
        const int qt0 = qs * 128;
        const int nt  = qs + 1;
        const int qgl = qt0 + w * 32 + l31;

        bf16x8_t qreg[4];
#pragma unroll
        for (int ks = 0; ks < 4; ++ks) {
            bf16x8_t qr = *(const bf16x8_t*)&qg[(size_t)qgl * LD + ks * 16 + 8 * hi];
            union { unsigned u[4]; bf16x8_t v; } pq;
#pragma unroll
            for (int j = 0; j < 4; ++j)
                pq.u[j] = pk_bf16((float)qr[2 * j] * CE, (float)qr[2 * j + 1] * CE);
            qreg[ks] = pq.v;
        }

        bf16x8_t kreg[4], vreg[4];
#pragma unroll
        for (int jj = 0; jj < 4; ++jj)
            kreg[jj] = *(const bf16x8_t*)&kg[(size_t)(kr8 + 32 * jj) * LD + kc * 8];
#pragma unroll
        for (int jj = 0; jj < 4; ++jj)
            vreg[jj] = *(const bf16x8_t*)&Vgb[(size_t)(vd8 + 16 * jj) * 2048 + vc * 8];

        f32x16_t o0 = (f32x16_t)(0.f), o1 = (f32x16_t)(0.f);
        f32x16_t o2 = (f32x16_t)(0.f);
        float m_r = -3.0e38f;

        __syncthreads();   // pass boundary

        for (int t = 0; t < nt; ++t) {
            __bf16* Kb = Ks[t & 1];
            __bf16* Vb = Vt[t & 1];

#pragma unroll
            for (int jj = 0; jj < 4; ++jj)
                *(bf16x8_t*)&Kb[(kr8 + 32 * jj) * 64 + kslot] = kreg[jj];
#pragma unroll
            for (int jj = 0; jj < 4; ++jj)
                *(bf16x8_t*)&Vb[(vd8 + 16 * jj) * 128 + vslot] = vreg[jj];

            __syncthreads();

            if (t + 1 < nt) {
                const size_t kb0 = (size_t)(t + 1) * 128;
#pragma unroll
                for (int jj = 0; jj < 4; ++jj)
                    kreg[jj] = *(const bf16x8_t*)&kg[(kb0 + kr8 + 32 * jj) * LD + kc * 8];
#pragma unroll
                for (int jj = 0; jj < 4; ++jj)
                    vreg[jj] = *(const bf16x8_t*)&Vgb[(size_t)(vd8 + 16 * jj) * 2048 + kb0 + vc * 8];
            }

            f32x16_t s[4];
            __builtin_amdgcn_s_setprio(1);
#pragma unroll
            for (int kb = 0; kb < 4; ++kb) {
                const int key = kb * 32 + l31;
                const int sw7 = key & 7;
                s[kb] = (f32x16_t)(0.f);
#pragma unroll
                for (int ks = 0; ks < 4; ++ks) {
                    bf16x8_t kf = *(const bf16x8_t*)&Kb[key * 64 + (((2 * ks + hi) ^ sw7) << 3)];
                    s[kb] = __builtin_amdgcn_mfma_f32_32x32x16_bf16(kf, qreg[ks], s[kb], 0, 0, 0);
                }
            }
            __builtin_amdgcn_s_setprio(0);

            if (t == nt - 1) {
                const int ql = w * 32 + l31;
#pragma unroll
                for (int kb = 0; kb < 4; ++kb)
#pragma unroll
                    for (int r = 0; r < 16; ++r) {
                        const int key = kb * 32 + (r & 3) + 8 * (r >> 2) + 4 * hi;
                        if (key > ql) s[kb][r] = -1.0e30f;
                    }
            }

            float pm = -3.0e38f;
#pragma unroll
            for (int kb = 0; kb < 4; ++kb) {
                float a = fmaxf(fmaxf(s[kb][0], s[kb][1]), s[kb][2]);
                a = fmaxf(fmaxf(a, s[kb][3]), s[kb][4]);
                a = fmaxf(fmaxf(a, s[kb][5]), s[kb][6]);
                a = fmaxf(fmaxf(a, s[kb][7]), s[kb][8]);
                a = fmaxf(fmaxf(a, s[kb][9]), s[kb][10]);
                a = fmaxf(fmaxf(a, s[kb][11]), s[kb][12]);
                a = fmaxf(fmaxf(a, s[kb][13]), s[kb][14]);
                a = fmaxf(a, s[kb][15]);
                pm = fmaxf(pm, a);
            }

            if (!__all(pm <= m_r + DEFER)) {
                pm = fmaxf(pm, __shfl_xor(pm, 32));
                const float mn    = fmaxf(m_r, pm);
                const float alpha = exp2f(m_r - mn);
                o2[0] *= alpha;
#pragma unroll
                for (int r = 0; r < 16; ++r) { o0[r] *= alpha; o1[r] *= alpha; }
                m_r = mn;
            }
            const float mr = m_r;

#pragma unroll
            for (int kb = 0; kb < 4; ++kb)
#pragma unroll
                for (int r = 0; r < 16; ++r)
                    s[kb][r] = exp2f(s[kb][r] - mr);

            __builtin_amdgcn_s_setprio(1);
#pragma unroll
            for (int ks = 0; ks < 8; ++ks) {
                const int kb = ks >> 1;
                const int rb = 8 * (ks & 1);
                unsigned L0 = pk_bf16(s[kb][rb + 0], s[kb][rb + 1]);
                unsigned L1 = pk_bf16(s[kb][rb + 2], s[kb][rb + 3]);
                unsigned H0 = pk_bf16(s[kb][rb + 4], s[kb][rb + 5]);
                unsigned H1 = pk_bf16(s[kb][rb + 6], s[kb][rb + 7]);
                asm("v_permlane32_swap_b32 %0, %1" : "+v"(L0), "+v"(H0));
                asm("v_permlane32_swap_b32 %0, %1" : "+v"(L1), "+v"(H1));
                union { unsigned u[4]; bf16x8_t v; } uf;
                uf.u[0] = L0; uf.u[1] = L1; uf.u[2] = H0; uf.u[3] = H1;
                const int gv = 2 * ks + hi;
                {
                    const int d = l31;
                    bf16x8_t vf = *(const bf16x8_t*)&Vb[d * 128 + ((gv ^ (d & 7)) << 3)];
                    o0 = __builtin_amdgcn_mfma_f32_32x32x16_bf16(vf, uf.v, o0, 0, 0, 0);
                }
                {
                    const int d = 32 + l31;
                    bf16x8_t vf = *(const bf16x8_t*)&Vb[d * 128 + ((gv ^ (d & 7)) << 3)];
                    o1 = __builtin_amdgcn_mfma_f32_32x32x16_bf16(vf, uf.v, o1, 0, 0, 0);
                }
                o2 = __builtin_amdgcn_mfma_f32_32x32x16_bf16(ones8, uf.v, o2, 0, 0, 0);
            }
            __builtin_amdgcn_s_setprio(0);
        }

        const float inv = 1.0f / o2[0];
        __bf16* yrow = y + (size_t)(b * T + qgl) * 1024 + h * 64;
#pragma unroll
        for (int tq = 0; tq < 4; ++tq) {
            bf16x4_t ov0, ov1;
#pragma unroll
            for (int u = 0; u < 4; ++u) {
                ov0[u] = (__bf16)(o0[tq * 4 + u] * inv);
                ov1[u] = (__bf16)(o1[tq * 4 + u] * inv);
            }
            const int dl = 8 * tq + 4 * hi;
            *(bf16x4_t*)&yrow[dl]      = ov0;
            *(bf16x4_t*)&yrow[32 + dl] = ov1;
        }
    }
}

// ---------------- launch ----------------
extern "C" void kernel_launch(void* const* d_in, const int* in_sizes, int n_in,
                              void* d_out, int out_size, void* d_ws, size_t ws_size,
                              hipStream_t stream) {
    const float* x      = (const float*)d_in[0];
    const float* w_attn = (const float*)d_in[1];
    const float* w_proj = (const float*)d_in[2];
    float* out = (float*)d_out;

    char* ws = (char*)d_ws;
    __bf16* xb   = (__bf16*)(ws);                      // 8192*1024      = 16 MB
    __bf16* wab  = (__bf16*)(ws + 16777216);           // 3072*1024      = 6 MB
    __bf16* wpb  = (__bf16*)(ws + 23068672);           // 1024*1024      = 2 MB
    __bf16* qkvb = (__bf16*)(ws + 25165824);           // 8192*2048 Q|K  = 32 MB
    __bf16* yb   = (__bf16*)(ws + 58720256);           // 8192*1024      = 16 MB
    __bf16* Vg   = (__bf16*)(ws + 75497472);           // 64*64*2048     = 16 MB

    f2bf3_kernel<<<12288, 256, 0, stream>>>(x, w_attn, w_proj, xb, wab, wpb);

    // qkv: Q/K -> qkvb [8192][2048]; V -> Vg transposed  (256x192 8-phase, 512 blocks)
    gemm1_m201<<<512, 512, 0, stream>>>(xb, wab, qkvb, Vg, 8192, 3072, 1024);

    // flash attention -> yb [8192, 1024]
    attn_kernel<<<512, 256, 0, stream>>>(qkvb, Vg, yb);

    // out = yb @ w_proj^T  [8192, 1024] fp32  (256x128 8-phase, 256 blocks)
    gemm2_m201<<<256, 512, 0, stream>>>(yb, wpb, out, 8192, 1024, 1024);
}

// Round 20
// 168.134 us; speedup vs baseline: 1.0465x; 1.0409x over previous
//
#include <hip/hip_runtime.h>
#include <hip/hip_bf16.h>

typedef __bf16 bf16x8_t __attribute__((ext_vector_type(8)));
typedef __bf16 bf16x4_t __attribute__((ext_vector_type(4)));
typedef float f32x4_t __attribute__((ext_vector_type(4)));
typedef float f32x16_t __attribute__((ext_vector_type(16)));

__device__ __forceinline__ void gload_lds16(const void* g, void* l) {
    __builtin_amdgcn_global_load_lds((const __attribute__((address_space(1))) void*)g,
                                     (__attribute__((address_space(3))) void*)l, 16, 0, 0);
}

__device__ __forceinline__ unsigned pk_bf16(float a, float b) {
    unsigned r;
    asm("v_cvt_pk_bf16_f32 %0, %1, %2" : "=v"(r) : "v"(a), "v"(b));
    return r;
}

// ---------------- fused fp32 -> bf16 conversion (x, w_attn, w_proj) ----------------
__global__ void f2bf3_kernel(const float* __restrict__ x, const float* __restrict__ wa,
                             const float* __restrict__ wp, __bf16* __restrict__ xb,
                             __bf16* __restrict__ wab, __bf16* __restrict__ wpb) {
    int i = blockIdx.x * blockDim.x + threadIdx.x;   // float4 index, total 3145728
    const float* in; __bf16* out; int off;
    if (i < 2097152)      { in = x;  out = xb;  off = i; }
    else if (i < 2883584) { in = wa; out = wab; off = i - 2097152; }
    else                  { in = wp; out = wpb; off = i - 2883584; }
    float4 v = *(const float4*)(in + off * 4);
    bf16x4_t o;
    o[0] = (__bf16)v.x; o[1] = (__bf16)v.y; o[2] = (__bf16)v.z; o[3] = (__bf16)v.w;
    *(bf16x4_t*)(out + off * 4) = o;
}

// ---------------- GEMM1: 256x192 8-phase, BK=64, 512 blocks (R15/R17 proven, n-minor map) ----------------
__global__ __launch_bounds__(512, 2) void gemm1_m201(const __bf16* __restrict__ A,
                                                     const __bf16* __restrict__ Bt,
                                                     __bf16* __restrict__ Cqk,
                                                     __bf16* __restrict__ Vg,
                                                     int M, int N, int K) {
    __shared__ __bf16 As[2][256 * 64];
    __shared__ __bf16 Bs[2][192 * 64];

    const int tid  = threadIdx.x;
    const int lane = tid & 63;
    const int wid  = tid >> 6;
    const int wm   = wid >> 2;
    const int wn   = wid & 3;

    int fl = blockIdx.x;
    fl = (fl & 7) * (gridDim.x >> 3) + (fl >> 3);   // 512 % 8 == 0 -> bijective
    const int m0 = (fl >> 4) * 256;
    const int n0 = (fl & 15) * 192;

    const int lr = lane & 15;
    const int lg = lane >> 4;
    const int cr = lg * 4;
    const int srow = lane >> 3;
    const int gcol = (((lane & 7) ^ srow) << 3);

    f32x4_t acc[8][3];
#pragma unroll
    for (int i = 0; i < 8; ++i)
#pragma unroll
        for (int j = 0; j < 3; ++j)
            acc[i][j] = (f32x4_t){0.f, 0.f, 0.f, 0.f};

    const int NT = K >> 6;
    const int NI = NT >> 1;

    bf16x8_t af[4][2], bf0[2][2], bf1[1][2];

    auto stA = [&](int kt, int buf, int half) {
        const __bf16* Ab = A + (size_t)m0 * K + (size_t)kt * 64;
        const int s0 = half * 16 + wid, s1 = s0 + 8;
        gload_lds16(Ab + (size_t)(s0 * 8 + srow) * K + gcol, &As[buf][s0 * 512]);
        gload_lds16(Ab + (size_t)(s1 * 8 + srow) * K + gcol, &As[buf][s1 * 512]);
    };
    auto stBlo = [&](int kt, int buf) {
        const __bf16* Bb = Bt + (size_t)n0 * K + (size_t)kt * 64;
        gload_lds16(Bb + (size_t)(wid * 8 + srow) * K + gcol, &Bs[buf][wid * 512]);
        gload_lds16(Bb + (size_t)((wid + 8) * 8 + srow) * K + gcol, &Bs[buf][(wid + 8) * 512]);
    };
    auto stBhi = [&](int kt, int buf) {
        const __bf16* Bb = Bt + (size_t)n0 * K + (size_t)kt * 64;
        gload_lds16(Bb + (size_t)((wid + 16) * 8 + srow) * K + gcol, &Bs[buf][(wid + 16) * 512]);
    };
    auto dsA = [&](const __bf16* Ab, int mfh) {
#pragma unroll
        for (int mf = 0; mf < 4; ++mf)
#pragma unroll
            for (int kk = 0; kk < 2; ++kk) {
                const int row = wm * 128 + (mfh * 4 + mf) * 16 + lr;
                const int g   = kk * 4 + lg;
                af[mf][kk] = *(const bf16x8_t*)&Ab[row * 64 + ((g ^ (row & 7)) << 3)];
            }
    };
    auto dsB0 = [&](const __bf16* Bb) {
#pragma unroll
        for (int nfp = 0; nfp < 2; ++nfp)
#pragma unroll
            for (int kk = 0; kk < 2; ++kk) {
                const int row = wn * 48 + nfp * 16 + lr;
                const int g   = kk * 4 + lg;
                bf0[nfp][kk] = *(const bf16x8_t*)&Bb[row * 64 + ((g ^ (row & 7)) << 3)];
            }
    };
    auto dsB1 = [&](const __bf16* Bb) {
#pragma unroll
        for (int kk = 0; kk < 2; ++kk) {
            const int row = wn * 48 + 2 * 16 + lr;
            const int g   = kk * 4 + lg;
            bf1[0][kk] = *(const bf16x8_t*)&Bb[row * 64 + ((g ^ (row & 7)) << 3)];
        }
    };
    auto MF0 = [&](int mfh) {
        __builtin_amdgcn_s_setprio(1);
#pragma unroll
        for (int mf = 0; mf < 4; ++mf)
#pragma unroll
            for (int nfp = 0; nfp < 2; ++nfp) {
                const int ai = mfh * 4 + mf;
                acc[ai][nfp] = __builtin_amdgcn_mfma_f32_16x16x32_bf16(af[mf][0], bf0[nfp][0], acc[ai][nfp], 0, 0, 0);
                acc[ai][nfp] = __builtin_amdgcn_mfma_f32_16x16x32_bf16(af[mf][1], bf0[nfp][1], acc[ai][nfp], 0, 0, 0);
            }
        __builtin_amdgcn_s_setprio(0);
    };
    auto MF1 = [&](int mfh) {
        __builtin_amdgcn_s_setprio(1);
#pragma unroll
        for (int mf = 0; mf < 4; ++mf) {
            const int ai = mfh * 4 + mf;
            acc[ai][2] = __builtin_amdgcn_mfma_f32_16x16x32_bf16(af[mf][0], bf1[0][0], acc[ai][2], 0, 0, 0);
            acc[ai][2] = __builtin_amdgcn_mfma_f32_16x16x32_bf16(af[mf][1], bf1[0][1], acc[ai][2], 0, 0, 0);
        }
        __builtin_amdgcn_s_setprio(0);
    };

#define BAR() __builtin_amdgcn_s_barrier()
#define LGK0() asm volatile("s_waitcnt lgkmcnt(0)" ::: "memory")

    stA(0, 0, 0); stA(0, 0, 1); stBlo(0, 0); stBhi(0, 0);
    stBlo(1, 1); stBhi(1, 1);
    asm volatile("s_waitcnt vmcnt(3)" ::: "memory");
    BAR();

    for (int it = 0; it < NI; ++it) {
        const int t1 = 2 * it + 1, t2 = 2 * it + 2, t3 = 2 * it + 3;
        const bool lastit = (it == NI - 1);

        dsA(As[0], 0); dsB0(Bs[0]);
        stA(t1, 1, 0);
        BAR(); LGK0();
        MF0(0);
        BAR();

        dsB1(Bs[0]);
        stA(t1, 1, 1);
        BAR(); LGK0();
        MF1(0);
        BAR();

        dsA(As[0], 1);
        if (!lastit) stBlo(t2, 0);
        BAR(); LGK0();
        MF0(1);
        BAR();

        if (!lastit) stBhi(t2, 0);
        if (lastit) asm volatile("s_waitcnt vmcnt(0)" ::: "memory");
        else        asm volatile("s_waitcnt vmcnt(3)" ::: "memory");
        BAR();
        MF1(1);
        BAR();

        dsA(As[1], 0); dsB0(Bs[1]);
        if (!lastit) stA(t2, 0, 0);
        BAR(); LGK0();
        MF0(0);
        BAR();

        dsB1(Bs[1]);
        if (!lastit) stA(t2, 0, 1);
        BAR(); LGK0();
        MF1(0);
        BAR();

        dsA(As[1], 1);
        if (!lastit) stBlo(t3, 1);
        BAR(); LGK0();
        MF0(1);
        BAR();

        if (!lastit) stBhi(t3, 1);
        if (lastit) asm volatile("s_waitcnt vmcnt(0)" ::: "memory");
        else        asm volatile("s_waitcnt vmcnt(3)" ::: "memory");
        BAR();
        MF1(1);
        BAR();
    }
#undef BAR
#undef LGK0

#pragma unroll
    for (int mf = 0; mf < 8; ++mf) {
        const int row0 = m0 + wm * 128 + mf * 16 + cr;
        const int bb   = row0 >> 11;
        const int tt   = row0 & 2047;
#pragma unroll
        for (int nf = 0; nf < 3; ++nf) {
            const int colb = n0 + wn * 48 + nf * 16;
            if (colb < 2048) {
#pragma unroll
                for (int r = 0; r < 4; ++r)
                    Cqk[(size_t)(row0 + r) * 2048 + colb + lr] = (__bf16)acc[mf][nf][r];
            } else {
                const int c3 = colb + lr - 2048;
                const int hh = c3 >> 6, dd = c3 & 63;
                bf16x4_t pv;
#pragma unroll
                for (int r = 0; r < 4; ++r) pv[r] = (__bf16)acc[mf][nf][r];
                *(bf16x4_t*)&Vg[((size_t)(bb * 16 + hh) * 64 + dd) * 2048 + tt] = pv;
            }
        }
    }
}

// ---------------- GEMM2: 256x128 8-phase, BK=64, 256 blocks (R17 proven) ----------------
__global__ __launch_bounds__(512, 2) void gemm2_m201(const __bf16* __restrict__ A,
                                                     const __bf16* __restrict__ Bt,
                                                     float* __restrict__ C,
                                                     int M, int N, int K) {
    __shared__ __bf16 As[2][256 * 64];
    __shared__ __bf16 Bs[2][128 * 64];

    const int tid  = threadIdx.x;
    const int lane = tid & 63;
    const int wid  = tid >> 6;
    const int wm   = wid >> 2;
    const int wn   = wid & 3;

    int fl = blockIdx.x;
    fl = (fl & 7) * (gridDim.x >> 3) + (fl >> 3);
    const int m0 = (fl >> 3) * 256;
    const int n0 = (fl & 7) * 128;

    const int lr = lane & 15;
    const int lg = lane >> 4;
    const int cr = lg * 4;
    const int srow = lane >> 3;
    const int gcol = (((lane & 7) ^ srow) << 3);

    f32x4_t acc[8][2];
#pragma unroll
    for (int i = 0; i < 8; ++i)
#pragma unroll
        for (int j = 0; j < 2; ++j)
            acc[i][j] = (f32x4_t){0.f, 0.f, 0.f, 0.f};

    const int NT = K >> 6;
    const int NI = NT >> 1;

    bf16x8_t af[4][2], bf0[1][2], bf1[1][2];

    auto stA = [&](int kt, int buf, int half) {
        const __bf16* Ab = A + (size_t)m0 * K + (size_t)kt * 64;
        const int s0 = half * 16 + wid, s1 = s0 + 8;
        gload_lds16(Ab + (size_t)(s0 * 8 + srow) * K + gcol, &As[buf][s0 * 512]);
        gload_lds16(Ab + (size_t)(s1 * 8 + srow) * K + gcol, &As[buf][s1 * 512]);
    };
    auto stBlo = [&](int kt, int buf) {
        const __bf16* Bb = Bt + (size_t)n0 * K + (size_t)kt * 64;
        gload_lds16(Bb + (size_t)(wid * 8 + srow) * K + gcol, &Bs[buf][wid * 512]);
    };
    auto stBhi = [&](int kt, int buf) {
        const __bf16* Bb = Bt + (size_t)n0 * K + (size_t)kt * 64;
        gload_lds16(Bb + (size_t)((wid + 8) * 8 + srow) * K + gcol, &Bs[buf][(wid + 8) * 512]);
    };
    auto dsA = [&](const __bf16* Ab, int mfh) {
#pragma unroll
        for (int mf = 0; mf < 4; ++mf)
#pragma unroll
            for (int kk = 0; kk < 2; ++kk) {
                const int row = wm * 128 + (mfh * 4 + mf) * 16 + lr;
                const int g   = kk * 4 + lg;
                af[mf][kk] = *(const bf16x8_t*)&Ab[row * 64 + ((g ^ (row & 7)) << 3)];
            }
    };
    auto dsB0 = [&](const __bf16* Bb) {
#pragma unroll
        for (int kk = 0; kk < 2; ++kk) {
            const int row = wn * 32 + lr;
            const int g   = kk * 4 + lg;
            bf0[0][kk] = *(const bf16x8_t*)&Bb[row * 64 + ((g ^ (row & 7)) << 3)];
        }
    };
    auto dsB1 = [&](const __bf16* Bb) {
#pragma unroll
        for (int kk = 0; kk < 2; ++kk) {
            const int row = wn * 32 + 16 + lr;
            const int g   = kk * 4 + lg;
            bf1[0][kk] = *(const bf16x8_t*)&Bb[row * 64 + ((g ^ (row & 7)) << 3)];
        }
    };
    auto MF0 = [&](int mfh) {
        __builtin_amdgcn_s_setprio(1);
#pragma unroll
        for (int mf = 0; mf < 4; ++mf) {
            const int ai = mfh * 4 + mf;
            acc[ai][0] = __builtin_amdgcn_mfma_f32_16x16x32_bf16(af[mf][0], bf0[0][0], acc[ai][0], 0, 0, 0);
            acc[ai][0] = __builtin_amdgcn_mfma_f32_16x16x32_bf16(af[mf][1], bf0[0][1], acc[ai][0], 0, 0, 0);
        }
        __builtin_amdgcn_s_setprio(0);
    };
    auto MF1 = [&](int mfh) {
        __builtin_amdgcn_s_setprio(1);
#pragma unroll
        for (int mf = 0; mf < 4; ++mf) {
            const int ai = mfh * 4 + mf;
            acc[ai][1] = __builtin_amdgcn_mfma_f32_16x16x32_bf16(af[mf][0], bf1[0][0], acc[ai][1], 0, 0, 0);
            acc[ai][1] = __builtin_amdgcn_mfma_f32_16x16x32_bf16(af[mf][1], bf1[0][1], acc[ai][1], 0, 0, 0);
        }
        __builtin_amdgcn_s_setprio(0);
    };

#define BAR() __builtin_amdgcn_s_barrier()
#define LGK0() asm volatile("s_waitcnt lgkmcnt(0)" ::: "memory")

    stA(0, 0, 0); stA(0, 0, 1); stBlo(0, 0); stBhi(0, 0);
    stBlo(1, 1); stBhi(1, 1);
    asm volatile("s_waitcnt vmcnt(2)" ::: "memory");
    BAR();

    for (int it = 0; it < NI; ++it) {
        const int t1 = 2 * it + 1, t2 = 2 * it + 2, t3 = 2 * it + 3;
        const bool lastit = (it == NI - 1);

        dsA(As[0], 0); dsB0(Bs[0]);
        stA(t1, 1, 0);
        BAR(); LGK0();
        MF0(0);
        BAR();

        dsB1(Bs[0]);
        stA(t1, 1, 1);
        BAR(); LGK0();
        MF1(0);
        BAR();

        dsA(As[0], 1);
        if (!lastit) stBlo(t2, 0);
        BAR(); LGK0();
        MF0(1);
        BAR();

        if (!lastit) stBhi(t2, 0);
        if (lastit) asm volatile("s_waitcnt vmcnt(0)" ::: "memory");
        else        asm volatile("s_waitcnt vmcnt(2)" ::: "memory");
        BAR();
        MF1(1);
        BAR();

        dsA(As[1], 0); dsB0(Bs[1]);
        if (!lastit) stA(t2, 0, 0);
        BAR(); LGK0();
        MF0(0);
        BAR();

        dsB1(Bs[1]);
        if (!lastit) stA(t2, 0, 1);
        BAR(); LGK0();
        MF1(0);
        BAR();

        dsA(As[1], 1);
        if (!lastit) stBlo(t3, 1);
        BAR(); LGK0();
        MF0(1);
        BAR();

        if (!lastit) stBhi(t3, 1);
        if (lastit) asm volatile("s_waitcnt vmcnt(0)" ::: "memory");
        else        asm volatile("s_waitcnt vmcnt(2)" ::: "memory");
        BAR();
        MF1(1);
        BAR();
    }
#undef BAR
#undef LGK0

#pragma unroll
    for (int mf = 0; mf < 8; ++mf) {
        const int row0 = m0 + wm * 128 + mf * 16 + cr;
#pragma unroll
        for (int nf = 0; nf < 2; ++nf) {
            const int col = n0 + wn * 32 + nf * 16 + lr;
#pragma unroll
            for (int r = 0; r < 4; ++r)
                C[(size_t)(row0 + r) * 1024 + col] = acc[mf][nf][r];
        }
    }
}

// ---------------- flash attention (causal), v12 (R16/R17 best) ----------------
__global__ __launch_bounds__(256, 2) void attn_kernel(const __bf16* __restrict__ qkv,  // [8192][2048] Q|K
                                                      const __bf16* __restrict__ Vg,   // [(b*16+h)*64+d][2048]
                                                      __bf16* __restrict__ y) {
    const int T = 2048, LD = 2048;
    const int orig = blockIdx.x;
    const int bidx = ((orig & 7) << 6) + (orig >> 3);   // XCD swizzle (512 % 8 == 0)
    const int pair = bidx & 7;
    const int h    = (bidx >> 3) & 15;
    const int b    = bidx >> 7;

    __shared__ __bf16 Ks[2][128 * 64];
    __shared__ __bf16 Vt[2][64 * 128];

    const int tid  = threadIdx.x;
    const int lane = tid & 63;
    const int w    = tid >> 6;
    const int l31  = lane & 31;
    const int hi   = lane >> 5;

    const __bf16* qg  = qkv + (size_t)b * T * LD + h * 64;
    const __bf16* kg  = qg + 1024;
    const __bf16* Vgb = Vg + (size_t)(b * 16 + h) * 64 * 2048;

    const float CE    = 0.125f * 1.44269504f;
    const float DEFER = 8.0f;

    const int kc = tid & 7;
    const int kr8 = tid >> 3;
    const int kslot = (kc ^ (kr8 & 7)) << 3;
    const int vc = tid & 15;
    const int vd8 = tid >> 4;
    const int vslot = (vc ^ (vd8 & 7)) << 3;

    bf16x8_t ones8;
#pragma unroll
    for (int j = 0; j < 8; ++j) ones8[j] = (__bf16)1.0f;

    for (int pass = 0; pass < 2; ++pass) {
        const int qs  = pass ? 15 - pair : pair;
        const int qt0 = qs * 128;
        const int nt  = qs + 1;
        const int qgl = qt0 + w * 32 + l31;

        bf16x8_t qreg[4];
#pragma unroll
        for (int ks = 0; ks < 4; ++ks) {
            bf16x8_t qr = *(const bf16x8_t*)&qg[(size_t)qgl * LD + ks * 16 + 8 * hi];
            union { unsigned u[4]; bf16x8_t v; } pq;
#pragma unroll
            for (int j = 0; j < 4; ++j)
                pq.u[j] = pk_bf16((float)qr[2 * j] * CE, (float)qr[2 * j + 1] * CE);
            qreg[ks] = pq.v;
        }

        bf16x8_t kreg[4], vreg[4];
#pragma unroll
        for (int jj = 0; jj < 4; ++jj)
            kreg[jj] = *(const bf16x8_t*)&kg[(size_t)(kr8 + 32 * jj) * LD + kc * 8];
#pragma unroll
        for (int jj = 0; jj < 4; ++jj)
            vreg[jj] = *(const bf16x8_t*)&Vgb[(size_t)(vd8 + 16 * jj) * 2048 + vc * 8];

        f32x16_t o0 = (f32x16_t)(0.f), o1 = (f32x16_t)(0.f);
        f32x16_t o2 = (f32x16_t)(0.f);
        float m_r = -3.0e38f;

        __syncthreads();   // pass boundary

        for (int t = 0; t < nt; ++t) {
            __bf16* Kb = Ks[t & 1];
            __bf16* Vb = Vt[t & 1];

#pragma unroll
            for (int jj = 0; jj < 4; ++jj)
                *(bf16x8_t*)&Kb[(kr8 + 32 * jj) * 64 + kslot] = kreg[jj];
#pragma unroll
            for (int jj = 0; jj < 4; ++jj)
                *(bf16x8_t*)&Vb[(vd8 + 16 * jj) * 128 + vslot] = vreg[jj];

            __syncthreads();

            if (t + 1 < nt) {
                const size_t kb0 = (size_t)(t + 1) * 128;
#pragma unroll
                for (int jj = 0; jj < 4; ++jj)
                    kreg[jj] = *(const bf16x8_t*)&kg[(kb0 + kr8 + 32 * jj) * LD + kc * 8];
#pragma unroll
                for (int jj = 0; jj < 4; ++jj)
                    vreg[jj] = *(const bf16x8_t*)&Vgb[(size_t)(vd8 + 16 * jj) * 2048 + kb0 + vc * 8];
            }

            f32x16_t s[4];
            __builtin_amdgcn_s_setprio(1);
#pragma unroll
            for (int kb = 0; kb < 4; ++kb) {
                const int key = kb * 32 + l31;
                const int sw7 = key & 7;
                s[kb] = (f32x16_t)(0.f);
#pragma unroll
                for (int ks = 0; ks < 4; ++ks) {
                    bf16x8_t kf = *(const bf16x8_t*)&Kb[key * 64 + (((2 * ks + hi) ^ sw7) << 3)];
                    s[kb] = __builtin_amdgcn_mfma_f32_32x32x16_bf16(kf, qreg[ks], s[kb], 0, 0, 0);
                }
            }
            __builtin_amdgcn_s_setprio(0);

            if (t == nt - 1) {
                const int ql = w * 32 + l31;
#pragma unroll
                for (int kb = 0; kb < 4; ++kb)
#pragma unroll
                    for (int r = 0; r < 16; ++r) {
                        const int key = kb * 32 + (r & 3) + 8 * (r >> 2) + 4 * hi;
                        if (key > ql) s[kb][r] = -1.0e30f;
                    }
            }

            float pm = -3.0e38f;
#pragma unroll
            for (int kb = 0; kb < 4; ++kb) {
                float a = fmaxf(fmaxf(s[kb][0], s[kb][1]), s[kb][2]);
                a = fmaxf(fmaxf(a, s[kb][3]), s[kb][4]);
                a = fmaxf(fmaxf(a, s[kb][5]), s[kb][6]);
                a = fmaxf(fmaxf(a, s[kb][7]), s[kb][8]);
                a = fmaxf(fmaxf(a, s[kb][9]), s[kb][10]);
                a = fmaxf(fmaxf(a, s[kb][11]), s[kb][12]);
                a = fmaxf(fmaxf(a, s[kb][13]), s[kb][14]);
                a = fmaxf(a, s[kb][15]);
                pm = fmaxf(pm, a);
            }

            if (!__all(pm <= m_r + DEFER)) {
                pm = fmaxf(pm, __shfl_xor(pm, 32));
                const float mn    = fmaxf(m_r, pm);
                const float alpha = exp2f(m_r - mn);
                o2[0] *= alpha;
#pragma unroll
                for (int r = 0; r < 16; ++r) { o0[r] *= alpha; o1[r] *= alpha; }
                m_r = mn;
            }
            const float mr = m_r;

#pragma unroll
            for (int kb = 0; kb < 4; ++kb)
#pragma unroll
                for (int r = 0; r < 16; ++r)
                    s[kb][r] = exp2f(s[kb][r] - mr);

            __builtin_amdgcn_s_setprio(1);
#pragma unroll
            for (int ks = 0; ks < 8; ++ks) {
                const int kb = ks >> 1;
                const int rb = 8 * (ks & 1);
                unsigned L0 = pk_bf16(s[kb][rb + 0], s[kb][rb + 1]);
                unsigned L1 = pk_bf16(s[kb][rb + 2], s[kb][rb + 3]);
                unsigned H0 = pk_bf16(s[kb][rb + 4], s[kb][rb + 5]);
                unsigned H1 = pk_bf16(s[kb][rb + 6], s[kb][rb + 7]);
                asm("v_permlane32_swap_b32 %0, %1" : "+v"(L0), "+v"(H0));
                asm("v_permlane32_swap_b32 %0, %1" : "+v"(L1), "+v"(H1));
                union { unsigned u[4]; bf16x8_t v; } uf;
                uf.u[0] = L0; uf.u[1] = L1; uf.u[2] = H0; uf.u[3] = H1;
                const int gv = 2 * ks + hi;
                {
                    const int d = l31;
                    bf16x8_t vf = *(const bf16x8_t*)&Vb[d * 128 + ((gv ^ (d & 7)) << 3)];
                    o0 = __builtin_amdgcn_mfma_f32_32x32x16_bf16(vf, uf.v, o0, 0, 0, 0);
                }
                {
                    const int d = 32 + l31;
                    bf16x8_t vf = *(const bf16x8_t*)&Vb[d * 128 + ((gv ^ (d & 7)) << 3)];
                    o1 = __builtin_amdgcn_mfma_f32_32x32x16_bf16(vf, uf.v, o1, 0, 0, 0);
                }
                o2 = __builtin_amdgcn_mfma_f32_32x32x16_bf16(ones8, uf.v, o2, 0, 0, 0);
            }
            __builtin_amdgcn_s_setprio(0);
        }

        const float inv = 1.0f / o2[0];
        __bf16* yrow = y + (size_t)(b * T + qgl) * 1024 + h * 64;
#pragma unroll
        for (int tq = 0; tq < 4; ++tq) {
            bf16x4_t ov0, ov1;
#pragma unroll
            for (int u = 0; u < 4; ++u) {
                ov0[u] = (__bf16)(o0[tq * 4 + u] * inv);
                ov1[u] = (__bf16)(o1[tq * 4 + u] * inv);
            }
            const int dl = 8 * tq + 4 * hi;
            *(bf16x4_t*)&yrow[dl]      = ov0;
            *(bf16x4_t*)&yrow[32 + dl] = ov1;
        }
    }
}

// ---------------- launch ----------------
extern "C" void kernel_launch(void* const* d_in, const int* in_sizes, int n_in,
                              void* d_out, int out_size, void* d_ws, size_t ws_size,
                              hipStream_t stream) {
    const float* x      = (const float*)d_in[0];
    const float* w_attn = (const float*)d_in[1];
    const float* w_proj = (const float*)d_in[2];
    float* out = (float*)d_out;

    char* ws = (char*)d_ws;
    __bf16* xb   = (__bf16*)(ws);                      // 8192*1024      = 16 MB
    __bf16* wab  = (__bf16*)(ws + 16777216);           // 3072*1024      = 6 MB
    __bf16* wpb  = (__bf16*)(ws + 23068672);           // 1024*1024      = 2 MB
    __bf16* qkvb = (__bf16*)(ws + 25165824);           // 8192*2048 Q|K  = 32 MB
    __bf16* yb   = (__bf16*)(ws + 58720256);           // 8192*1024      = 16 MB
    __bf16* Vg   = (__bf16*)(ws + 75497472);           // 64*64*2048     = 16 MB

    f2bf3_kernel<<<12288, 256, 0, stream>>>(x, w_attn, w_proj, xb, wab, wpb);

    // qkv: Q/K -> qkvb [8192][2048]; V -> Vg transposed  (256x192 8-phase, 512 blocks)
    gemm1_m201<<<512, 512, 0, stream>>>(xb, wab, qkvb, Vg, 8192, 3072, 1024);

    // flash attention -> yb [8192, 1024]
    attn_kernel<<<512, 256, 0, stream>>>(qkvb, Vg, yb);

    // out = yb @ w_proj^T  [8192, 1024] fp32  (256x128 8-phase, 256 blocks)
    gemm2_m201<<<256, 512, 0, stream>>>(yb, wpb, out, 8192, 1024, 1024);
}